// Round 5
// baseline (414.904 us; speedup 1.0000x reference)
//
#include <hip/hip_runtime.h>
#include <math.h>
#include <stdint.h>

#define N_NODES 100000
#define N_EDGES 1600000
#define IN_DIM  256
#define HID     128
#define EPS_C   0.3f
#define NB_SCAN 391   // ceil(N_NODES / 256)

typedef __attribute__((ext_vector_type(8))) __bf16 bf16x8;
typedef __attribute__((ext_vector_type(4))) float  f32x4;
typedef __attribute__((ext_vector_type(8))) unsigned short ushort8;

static __device__ __forceinline__ unsigned short f2bf(float f) {
    unsigned u = __float_as_uint(f);
    unsigned r = (u + 0x7fffu + ((u >> 16) & 1u)) >> 16;
    return (unsigned short)r;
}
static __device__ __forceinline__ float bf2f(unsigned short s) {
    return __uint_as_float((unsigned)s << 16);
}
// branch-free tanh: 1 - 2/(exp2(2x*log2e)+1); correct limits at +-inf
static __device__ __forceinline__ float fast_tanh(float x) {
    float e = __builtin_exp2f(x * 2.8853900817779268f);  // 2*log2(e)
    return 1.0f - 2.0f / (e + 1.0f);
}

// ---------------------------------------------------------------------------
// 1) Count incoming edges per dst (4 edges/thread, int4 reads).
// ---------------------------------------------------------------------------
__global__ __launch_bounds__(256) void count_kernel(const int* __restrict__ dst,
                                                    int* __restrict__ cnt) {
    int i = blockIdx.x * 256 + threadIdx.x;
    if (i * 4 >= N_EDGES) return;
    int4 d = *(const int4*)&dst[i * 4];
    atomicAdd(&cnt[d.x], 1);
    atomicAdd(&cnt[d.y], 1);
    atomicAdd(&cnt[d.z], 1);
    atomicAdd(&cnt[d.w], 1);
}

// ---------------------------------------------------------------------------
// 2) Exclusive scan of cnt -> rowstart; fused: nrm write + cnt zeroing
//    (zeroed cnt is reused by scatter as the slot counter).
// ---------------------------------------------------------------------------
__global__ __launch_bounds__(256) void block_sum_kernel(const int* __restrict__ cnt,
                                                        int* __restrict__ bsum) {
    __shared__ int s[256];
    int t = threadIdx.x;
    int i = blockIdx.x * 256 + t;
    s[t] = (i < N_NODES) ? cnt[i] : 0;
    __syncthreads();
    for (int off = 128; off > 0; off >>= 1) {
        if (t < off) s[t] += s[t + off];
        __syncthreads();
    }
    if (t == 0) bsum[blockIdx.x] = s[0];
}

__global__ __launch_bounds__(512) void scan_bsum_kernel(int* __restrict__ bsum) {
    __shared__ int s[512];
    int t = threadIdx.x;
    int v = (t < NB_SCAN) ? bsum[t] : 0;
    s[t] = v;
    __syncthreads();
    for (int off = 1; off < 512; off <<= 1) {
        int a = (t >= off) ? s[t - off] : 0;
        __syncthreads();
        s[t] += a;
        __syncthreads();
    }
    if (t < NB_SCAN) bsum[t] = s[t] - v;  // exclusive
}

__global__ __launch_bounds__(256) void scan_block_kernel(int* __restrict__ cnt,
                                                         const int* __restrict__ bsum,
                                                         int* __restrict__ rowstart,
                                                         float* __restrict__ nrm) {
    __shared__ int s[256];
    int t = threadIdx.x;
    int i = blockIdx.x * 256 + t;
    int v = (i < N_NODES) ? cnt[i] : 0;
    s[t] = v;
    __syncthreads();
    for (int off = 1; off < 256; off <<= 1) {
        int a = (t >= off) ? s[t - off] : 0;
        __syncthreads();
        s[t] += a;
        __syncthreads();
    }
    if (i < N_NODES) {
        rowstart[i] = bsum[blockIdx.x] + s[t] - v;
        nrm[i] = rsqrtf(fmaxf((float)v, 1.0f));
        cnt[i] = 0;  // reset: scatter reuses cnt as per-dst slot counter
    }
    if (i == 0) rowstart[N_NODES] = N_EDGES;
}

// ---------------------------------------------------------------------------
// w1 -> bf16 preconvert (one-time tiny kernel, 32768 elems)
// ---------------------------------------------------------------------------
__global__ __launch_bounds__(256) void convert_w1_kernel(const float* __restrict__ w1,
                                                         unsigned short* __restrict__ w1b) {
    int i = blockIdx.x * 256 + threadIdx.x;
    if (i * 4 >= HID * IN_DIM) return;
    float4 v = *(const float4*)&w1[i * 4];
    ushort4 r;
    r.x = f2bf(v.x); r.y = f2bf(v.y); r.z = f2bf(v.z); r.w = f2bf(v.w);
    *(ushort4*)&w1b[i * 4] = r;
}

// ---------------------------------------------------------------------------
// 3) MFMA GEMM: h = relu(x @ w1^T + b1), bf16, fused gate dots.
//    Block = 256 thr (4 waves), tile M=64 N=128, BK=32, 16x16x32 MFMA.
// ---------------------------------------------------------------------------
__global__ __launch_bounds__(256) void gemm_kernel(const float* __restrict__ x,
                                                   const unsigned short* __restrict__ w1b,
                                                   const float* __restrict__ b1,
                                                   const float* __restrict__ gw,
                                                   const float* __restrict__ nrm,
                                                   unsigned short* __restrict__ h,
                                                   float2* __restrict__ pd_pack,
                                                   float2* __restrict__ ps_pack) {
    __shared__ unsigned short As[64 * 40];   // [m][k] bf16, stride 40
    __shared__ unsigned short Bs[128 * 40];  // [n][k] bf16, stride 40

    int tid = threadIdx.x;
    int bm = blockIdx.x * 64;

    int wv   = tid >> 6;
    int lane = tid & 63;
    int col  = lane & 15;
    int kq   = lane >> 4;

    f32x4 acc[8];
#pragma unroll
    for (int nf = 0; nf < 8; nf++) acc[nf] = (f32x4){0.f, 0.f, 0.f, 0.f};

    int am = tid >> 2;            // 0..63
    int ak = (tid & 3) * 8;       // 0,8,16,24
    int bn = tid >> 1;            // 0..127
    int bk = (tid & 1) * 16;      // 0,16
    int agm = bm + am;

    for (int k0 = 0; k0 < IN_DIM; k0 += 32) {
        // stage A: 64x32 f32 -> bf16 (8 floats/thread)
        float4 a0 = {0,0,0,0}, a1 = {0,0,0,0};
        if (agm < N_NODES) {
            const float* p = &x[agm * IN_DIM + k0 + ak];
            a0 = *(const float4*)p;
            a1 = *(const float4*)(p + 4);
        }
        ushort8 av;
        av[0]=f2bf(a0.x); av[1]=f2bf(a0.y); av[2]=f2bf(a0.z); av[3]=f2bf(a0.w);
        av[4]=f2bf(a1.x); av[5]=f2bf(a1.y); av[6]=f2bf(a1.z); av[7]=f2bf(a1.w);
        // stage B: already bf16 (16 elems = 2 x ushort8 per thread, no convert)
        ushort8 bv0 = *(const ushort8*)&w1b[bn * IN_DIM + k0 + bk];
        ushort8 bv1 = *(const ushort8*)&w1b[bn * IN_DIM + k0 + bk + 8];

        __syncthreads();
        *(ushort8*)&As[am * 40 + ak] = av;
        *(ushort8*)&Bs[bn * 40 + bk] = bv0;
        *(ushort8*)&Bs[bn * 40 + bk + 8] = bv1;
        __syncthreads();

        bf16x8 afrag = *(bf16x8*)&As[(wv * 16 + col) * 40 + kq * 8];
#pragma unroll
        for (int nf = 0; nf < 8; nf++) {
            bf16x8 bfrag = *(bf16x8*)&Bs[(nf * 16 + col) * 40 + kq * 8];
            acc[nf] = __builtin_amdgcn_mfma_f32_16x16x32_bf16(afrag, bfrag, acc[nf], 0, 0, 0);
        }
    }

    float bias[8], wd[8], wsv[8];
#pragma unroll
    for (int nf = 0; nf < 8; nf++) {
        bias[nf] = b1[nf * 16 + col];
        wd[nf]   = gw[nf * 16 + col];
        wsv[nf]  = gw[HID + nf * 16 + col];
    }
#pragma unroll
    for (int r = 0; r < 4; r++) {
        int gm = bm + wv * 16 + kq * 4 + r;   // uniform across the 16 col-lanes
        float pd = 0.f, ps = 0.f;
        bool ok = (gm < N_NODES);
#pragma unroll
        for (int nf = 0; nf < 8; nf++) {
            float v = fmaxf(acc[nf][r] + bias[nf], 0.f);
            pd = fmaf(v, wd[nf], pd);
            ps = fmaf(v, wsv[nf], ps);
            if (ok) h[gm * HID + nf * 16 + col] = f2bf(v);
        }
#pragma unroll
        for (int m = 1; m < 16; m <<= 1) {
            pd += __shfl_xor(pd, m);
            ps += __shfl_xor(ps, m);
        }
        if (ok && col == 0) {
            float nv = nrm[gm];
            pd_pack[gm] = make_float2(pd, nv);
            ps_pack[gm] = make_float2(ps, nv);
        }
    }
}

// ---------------------------------------------------------------------------
// 4) Scatter: CSR permutation only — csrc[pos] = src. 4 B random stores
//    (halved line count vs 8 B epack -> L2 write-merging doubles).
// ---------------------------------------------------------------------------
__global__ __launch_bounds__(256) void scatter_kernel(const int* __restrict__ src,
                                                      const int* __restrict__ dst,
                                                      int* __restrict__ cnt,
                                                      const int* __restrict__ rowstart,
                                                      int* __restrict__ csrc) {
    int e = blockIdx.x * 256 + threadIdx.x;
    if (e >= N_EDGES) return;
    int d = dst[e];
    int pos = rowstart[d] + atomicAdd(&cnt[d], 1);
    csrc[pos] = src[e];
}

// ---------------------------------------------------------------------------
// 5) Aggregate: one wave per dst node; 4 edges in parallel per wave
//    (16 lanes x 8 channels each), unroll 2 -> 8 h-rows in flight.
//    Edge coefficient computed inline: tanh(a_dst[d]+a_src[s]+gb)*nrm_d*nrm_s.
//    ps_pack (800 KB) is L2-resident -> random 8 B loads are cheap.
// ---------------------------------------------------------------------------
__global__ __launch_bounds__(256) void aggregate_kernel(const int* __restrict__ rowstart,
                                                        const int* __restrict__ csrc,
                                                        const float2* __restrict__ pd_pack,
                                                        const float2* __restrict__ ps_pack,
                                                        const float* __restrict__ gb,
                                                        const unsigned short* __restrict__ h,
                                                        float* __restrict__ out) {
    int node = blockIdx.x * 4 + (threadIdx.x >> 6);
    if (node >= N_NODES) return;
    int lane = threadIdx.x & 63;
    int q  = lane >> 4;    // 0..3: edge slot within wave
    int ql = lane & 15;    // channel group: ch = ql*8

    int beg = rowstart[node];
    int end = rowstart[node + 1];

    float2 pdp = pd_pack[node];       // {a_dst[node], nrm[node]}
    float base = pdp.x + gb[0];
    float nd   = pdp.y;

    float acc[8];
#pragma unroll
    for (int t = 0; t < 8; t++) acc[t] = 0.f;

    int j = beg;
    for (; j + 8 <= end; j += 8) {
        int s0 = csrc[j + q];
        int s1 = csrc[j + 4 + q];
        float2 p0 = ps_pack[s0];      // {a_src, nrm_s} — L2 hit
        float2 p1 = ps_pack[s1];
        ushort8 r0 = *(const ushort8*)&h[s0 * HID + ql * 8];
        ushort8 r1 = *(const ushort8*)&h[s1 * HID + ql * 8];
        float c0 = fast_tanh(base + p0.x) * nd * p0.y;
        float c1 = fast_tanh(base + p1.x) * nd * p1.y;
#pragma unroll
        for (int t = 0; t < 8; t++) {
            acc[t] = fmaf(c0, bf2f(r0[t]), acc[t]);
            acc[t] = fmaf(c1, bf2f(r1[t]), acc[t]);
        }
    }
    for (; j < end; j += 4) {
        bool act = (j + q) < end;
        int idx = act ? (j + q) : beg;          // beg valid: j<end => beg<end
        int s = csrc[idx];
        float2 p = ps_pack[s];
        ushort8 r = *(const ushort8*)&h[s * HID + ql * 8];
        float c = act ? fast_tanh(base + p.x) * nd * p.y : 0.f;
#pragma unroll
        for (int t = 0; t < 8; t++) acc[t] = fmaf(c, bf2f(r[t]), acc[t]);
    }
    // combine the 4 edge-slots (lane bits 4,5)
#pragma unroll
    for (int t = 0; t < 8; t++) {
        acc[t] += __shfl_xor(acc[t], 16);
        acc[t] += __shfl_xor(acc[t], 32);
    }
    if (q == 0) {
        ushort8 hd = *(const ushort8*)&h[node * HID + ql * 8];
        f32x4 o0, o1;
        o0.x = fmaf(EPS_C, bf2f(hd[0]), acc[0]);
        o0.y = fmaf(EPS_C, bf2f(hd[1]), acc[1]);
        o0.z = fmaf(EPS_C, bf2f(hd[2]), acc[2]);
        o0.w = fmaf(EPS_C, bf2f(hd[3]), acc[3]);
        o1.x = fmaf(EPS_C, bf2f(hd[4]), acc[4]);
        o1.y = fmaf(EPS_C, bf2f(hd[5]), acc[5]);
        o1.z = fmaf(EPS_C, bf2f(hd[6]), acc[6]);
        o1.w = fmaf(EPS_C, bf2f(hd[7]), acc[7]);
        // nontemporal: out is never re-read; keep h resident in L2 instead
        __builtin_nontemporal_store(o0, (f32x4*)&out[node * HID + ql * 8]);
        __builtin_nontemporal_store(o1, (f32x4*)&out[node * HID + ql * 8 + 4]);
    }
}

// ---------------------------------------------------------------------------
extern "C" void kernel_launch(void* const* d_in, const int* in_sizes, int n_in,
                              void* d_out, int out_size, void* d_ws, size_t ws_size,
                              hipStream_t stream) {
    const float* x  = (const float*)d_in[0];
    const int*   ei = (const int*)d_in[1];
    const float* w1 = (const float*)d_in[2];
    const float* b1 = (const float*)d_in[3];
    const float* gw = (const float*)d_in[4];
    const float* gb = (const float*)d_in[5];
    float* out = (float*)d_out;

    const int* src = ei;
    const int* dst = ei + N_EDGES;

    uintptr_t base = (uintptr_t)d_ws;
    size_t off = 0;
    auto alloc = [&](size_t bytes) -> void* {
        void* p = (void*)(base + off);
        off += (bytes + 255) & ~(size_t)255;
        return p;
    };
    unsigned short* h   = (unsigned short*)alloc((size_t)N_NODES * HID * 2);  // 25.6 MB
    float2* pd_pack     = (float2*)alloc((size_t)N_NODES * 8);
    float2* ps_pack     = (float2*)alloc((size_t)N_NODES * 8);
    float*  nrm         = (float*)alloc((size_t)N_NODES * 4);
    int*    cnt         = (int*)alloc((size_t)N_NODES * 4);
    int*    rowstart    = (int*)alloc((size_t)(N_NODES + 1) * 4);
    int*    csrc        = (int*)alloc((size_t)N_EDGES * 4);
    int*    bsum        = (int*)alloc((size_t)NB_SCAN * 4);
    unsigned short* w1b = (unsigned short*)alloc((size_t)HID * IN_DIM * 2);

    (void)hipMemsetAsync(cnt, 0, (size_t)N_NODES * 4, stream);

    convert_w1_kernel<<<(HID * IN_DIM / 4 + 255) / 256, 256, 0, stream>>>(w1, w1b);
    count_kernel<<<(N_EDGES / 4 + 255) / 256, 256, 0, stream>>>(dst, cnt);
    block_sum_kernel<<<NB_SCAN, 256, 0, stream>>>(cnt, bsum);
    scan_bsum_kernel<<<1, 512, 0, stream>>>(bsum);
    scan_block_kernel<<<NB_SCAN, 256, 0, stream>>>(cnt, bsum, rowstart, nrm);
    gemm_kernel<<<(N_NODES + 63) / 64, 256, 0, stream>>>(x, w1b, b1, gw, nrm,
                                                         h, pd_pack, ps_pack);
    scatter_kernel<<<(N_EDGES + 255) / 256, 256, 0, stream>>>(src, dst, cnt, rowstart, csrc);
    aggregate_kernel<<<(N_NODES + 3) / 4, 256, 0, stream>>>(rowstart, csrc, pd_pack,
                                                            ps_pack, gb, h, out);
}